// Round 2
// baseline (330.333 us; speedup 1.0000x reference)
//
#include <hip/hip_runtime.h>
#include <math.h>

// SymmetryLoss: 3 plane reflections + 3 quaternion rotations of 1e6 points,
// nearest-grid-point distance (256^3x3 grid gather), plus tiny 3x3 regularizer.
// Gather-latency bound on random 12B gathers into the 201MB grid.
// R4: PTS_PER_THREAD=2 -> ONE batch of 12 gathers per thread (no inter-batch
// vmcnt drain, the R3 bug), __launch_bounds__(256,4) caps VGPR at 128 ->
// 16 waves/CU. Concurrency product (waves x depth) = 16x12 = 192, same as
// R2's 8x24, but with 2x the waves to cover ALU phases. Finalize stays folded
// (last-block ticket).

#define RGRID 256
#define PTS_PER_THREAD 2

__global__ void __launch_bounds__(256, 4)
symloss_main(const float* __restrict__ planes, const float* __restrict__ axes,
             const float* __restrict__ pts, const float* __restrict__ grid,
             const float* __restrict__ gmin, const float* __restrict__ gmax,
             float* __restrict__ acc, float* __restrict__ out, int N) {
    // Uniform-address parameter loads -> scalar registers
    float P[12], Q[12];
#pragma unroll
    for (int i = 0; i < 12; ++i) { P[i] = planes[i]; Q[i] = axes[i]; }
    const float g0 = gmin[0], g1 = gmin[1], g2 = gmin[2];
    const float s0 = 255.0f / (gmax[0] - g0);
    const float s1 = 255.0f / (gmax[1] - g1);
    const float s2 = 255.0f / (gmax[2] - g2);

    const int t  = blockIdx.x * blockDim.x + threadIdx.x;
    const int p0 = t * PTS_PER_THREAD;

    float lsum = 0.0f;
    if (p0 < N) {
        float px[2], py[2], pz[2];
        int npts;
        if (p0 + 1 < N) {
            // 2 points = 6 floats = 3 aligned float2 loads
            const float2* pts2 = (const float2*)pts;
            float2 a = pts2[3 * t + 0];
            float2 b = pts2[3 * t + 1];
            float2 c = pts2[3 * t + 2];
            px[0] = a.x; py[0] = a.y; pz[0] = b.x;
            px[1] = b.y; py[1] = c.x; pz[1] = c.y;
            npts = 2;
        } else {
            npts = 1;
            px[0] = pts[3 * p0 + 0];
            py[0] = pts[3 * p0 + 1];
            pz[0] = pts[3 * p0 + 2];
            px[1] = px[0]; py[1] = py[0]; pz[1] = pz[0];  // masked below
        }

        // 12 transformed points (2 pts x (3 reflections + 3 rotations))
        float tx[12], ty[12], tz[12];
#pragma unroll
        for (int i = 0; i < 2; ++i) {
            // 3 plane reflections: tp = p - 2*(p.n + d)*n
#pragma unroll
            for (int k = 0; k < 3; ++k) {
                float nx = P[4 * k + 0], ny = P[4 * k + 1], nz = P[4 * k + 2], d = P[4 * k + 3];
                float proj = px[i] * nx + py[i] * ny + pz[i] * nz + d;
                float m2p = -2.0f * proj;
                int o = i * 6 + k;
                tx[o] = fmaf(m2p, nx, px[i]);
                ty[o] = fmaf(m2p, ny, py[i]);
                tz[o] = fmaf(m2p, nz, pz[i]);
            }
            // 3 quaternion conjugations: o = (q * (0,p) * q_conj)[1:]
#pragma unroll
            for (int k = 0; k < 3; ++k) {
                float qw = Q[4 * k + 0], qx = Q[4 * k + 1], qy = Q[4 * k + 2], qz = Q[4 * k + 3];
                float rw = -(qx * px[i] + qy * py[i] + qz * pz[i]);
                float rx = qw * px[i] + qy * pz[i] - qz * py[i];
                float ry = qw * py[i] - qx * pz[i] + qz * px[i];
                float rz = qw * pz[i] + qx * py[i] - qy * px[i];
                int o = i * 6 + 3 + k;
                tx[o] = -rw * qx + rx * qw - ry * qz + rz * qy;
                ty[o] = -rw * qy + rx * qz + ry * qw - rz * qx;
                tz[o] = -rw * qz - rx * qy + ry * qx + rz * qw;
            }
        }

        // All 12 addresses first, then all 12 gathers issued before any
        // consumption -> 12-deep per-wave MLP, single batch, no drain bubble.
        int base[12];
#pragma unroll
        for (int o = 0; o < 12; ++o) {
            float f0 = rintf((tx[o] - g0) * s0);  // round-half-to-even == jnp.round
            float f1 = rintf((ty[o] - g1) * s1);
            float f2 = rintf((tz[o] - g2) * s2);
            f0 = fminf(fmaxf(f0, 0.0f), 255.0f);
            f1 = fminf(fmaxf(f1, 0.0f), 255.0f);
            f2 = fminf(fmaxf(f2, 0.0f), 255.0f);
            int i0 = (int)f0, i1 = (int)f1, i2 = (int)f2;
            base[o] = ((i0 * RGRID + i1) * RGRID + i2) * 3;
        }
        float cx[12], cy[12], cz[12];
#pragma unroll
        for (int o = 0; o < 12; ++o) {
            cx[o] = grid[base[o] + 0];
            cy[o] = grid[base[o] + 1];
            cz[o] = grid[base[o] + 2];
        }
        float partial[2] = {0.0f, 0.0f};
#pragma unroll
        for (int o = 0; o < 12; ++o) {
            float dx = tx[o] - cx[o], dy = ty[o] - cy[o], dz = tz[o] - cz[o];
            partial[o / 6] += sqrtf(fmaf(dx, dx, fmaf(dy, dy, dz * dz)));
        }
        lsum = partial[0];
        if (npts == 2) lsum += partial[1];
    }

    // wave(64) shuffle reduce -> LDS -> one atomic per block
#pragma unroll
    for (int off = 32; off > 0; off >>= 1)
        lsum += __shfl_down(lsum, off, 64);
    __shared__ float wsum[4];
    int lane = threadIdx.x & 63;
    int wid  = threadIdx.x >> 6;
    if (lane == 0) wsum[wid] = lsum;
    __syncthreads();

    if (threadIdx.x == 0) {
        atomicAdd(acc, wsum[0] + wsum[1] + wsum[2] + wsum[3]);
        __threadfence();
        unsigned prev = atomicAdd((unsigned*)(acc + 1), 1u);
        if (prev == gridDim.x - 1) {
            // Last block: all other blocks' adds visible (fence + atomic chain).
            float total = atomicAdd(acc, 0.0f);
            float sd = total / (float)N;

            // regularizer: sum((n n^T - I)^2) with UN-normalized plane normals
            float sA = 0.0f;
#pragma unroll
            for (int i = 0; i < 3; ++i)
#pragma unroll
                for (int j = 0; j < 3; ++j) {
                    float a = P[4 * i + 0] * P[4 * j + 0] + P[4 * i + 1] * P[4 * j + 1]
                            + P[4 * i + 2] * P[4 * j + 2] - (i == j ? 1.0f : 0.0f);
                    sA += a * a;
                }
            // sum((v v^T - I)^2) with normalized axis vectors
            float v[3][3];
#pragma unroll
            for (int i = 0; i < 3; ++i) {
                float vx = Q[4 * i + 1], vy = Q[4 * i + 2], vz = Q[4 * i + 3];
                float nrm = sqrtf(vx * vx + vy * vy + vz * vz);
                nrm = fmaxf(nrm, 1e-12f);
                v[i][0] = vx / nrm; v[i][1] = vy / nrm; v[i][2] = vz / nrm;
            }
            float sB = 0.0f;
#pragma unroll
            for (int i = 0; i < 3; ++i)
#pragma unroll
                for (int j = 0; j < 3; ++j) {
                    float b = v[i][0] * v[j][0] + v[i][1] * v[j][1] + v[i][2] * v[j][2]
                            - (i == j ? 1.0f : 0.0f);
                    sB += b * b;
                }

            float r = sA + sB;
            out[0] = sd + 25.0f * r;   // final_loss
            out[1] = sd;               // total_loss_sd
            out[2] = r;                // total_loss_r
        }
    }
}

extern "C" void kernel_launch(void* const* d_in, const int* in_sizes, int n_in,
                              void* d_out, int out_size, void* d_ws, size_t ws_size,
                              hipStream_t stream) {
    const float* planes = (const float*)d_in[0];   // (1,3,4)
    const float* axes   = (const float*)d_in[1];   // (1,3,4)
    const float* pts    = (const float*)d_in[2];   // (N,3)
    const float* grid   = (const float*)d_in[3];   // (256,256,256,3)
    const float* gmin   = (const float*)d_in[4];   // (3,)
    const float* gmax   = (const float*)d_in[5];   // (3,)
    float* out = (float*)d_out;
    float* acc = (float*)d_ws;                     // [0]=sum, [1]=ticket

    int N = in_sizes[2] / 3;

    hipMemsetAsync(acc, 0, 2 * sizeof(float), stream);

    int nthreads = (N + PTS_PER_THREAD - 1) / PTS_PER_THREAD;
    int blocks = (nthreads + 255) / 256;
    hipLaunchKernelGGL(symloss_main, dim3(blocks), dim3(256), 0, stream,
                       planes, axes, pts, grid, gmin, gmax, acc, out, N);
}

// Round 3
// 292.397 us; speedup vs baseline: 1.1297x; 1.1297x over previous
//
#include <hip/hip_runtime.h>
#include <math.h>

// SymmetryLoss: 3 plane reflections + 3 quaternion rotations of 1e6 points,
// nearest-grid-point distance (256^3x3 grid gather), plus tiny 3x3 regularizer.
// Gather-latency bound on random 12B gathers into the 201MB grid.
// R5: EXACT revert to the measured-266us R2 structure (PTS=4, plain
// __launch_bounds__(256), 24-deep single gather batch, ~200 VGPR -- the
// VGPR cap in R3/R4 made the compiler serialize the batch and regressed).
// Single delta vs baseline: finalize folded into main via last-block ticket.

#define RGRID 256
#define PTS_PER_THREAD 4

__global__ void __launch_bounds__(256)
symloss_main(const float* __restrict__ planes, const float* __restrict__ axes,
             const float* __restrict__ pts, const float* __restrict__ grid,
             const float* __restrict__ gmin, const float* __restrict__ gmax,
             float* __restrict__ acc, float* __restrict__ out, int N) {
    // Uniform-address parameter loads -> scalar registers
    float P[12], Q[12];
#pragma unroll
    for (int i = 0; i < 12; ++i) { P[i] = planes[i]; Q[i] = axes[i]; }
    const float g0 = gmin[0], g1 = gmin[1], g2 = gmin[2];
    const float s0 = 255.0f / (gmax[0] - g0);
    const float s1 = 255.0f / (gmax[1] - g1);
    const float s2 = 255.0f / (gmax[2] - g2);

    const int t  = blockIdx.x * blockDim.x + threadIdx.x;
    const int p0 = t * PTS_PER_THREAD;

    float lsum = 0.0f;
    if (p0 < N) {
        float px[4], py[4], pz[4];
        int npts;
        if (p0 + 3 < N) {
            // 4 points = 12 floats = 3 aligned float4 loads
            const float4* pts4 = (const float4*)pts;
            float4 a = pts4[3 * t + 0];
            float4 b = pts4[3 * t + 1];
            float4 c = pts4[3 * t + 2];
            px[0] = a.x; py[0] = a.y; pz[0] = a.z;
            px[1] = a.w; py[1] = b.x; pz[1] = b.y;
            px[2] = b.z; py[2] = b.w; pz[2] = c.x;
            px[3] = c.y; py[3] = c.z; pz[3] = c.w;
            npts = 4;
        } else {
            npts = N - p0;
#pragma unroll
            for (int i = 0; i < 4; ++i) {
                int p = p0 + (i < npts ? i : 0);   // clamp: duplicates are masked below
                px[i] = pts[3 * p + 0];
                py[i] = pts[3 * p + 1];
                pz[i] = pts[3 * p + 2];
            }
        }

        // 24 transformed points
        float tx[24], ty[24], tz[24];
#pragma unroll
        for (int i = 0; i < 4; ++i) {
            // 3 plane reflections: tp = p - 2*(p.n + d)*n
#pragma unroll
            for (int k = 0; k < 3; ++k) {
                float nx = P[4 * k + 0], ny = P[4 * k + 1], nz = P[4 * k + 2], d = P[4 * k + 3];
                float proj = px[i] * nx + py[i] * ny + pz[i] * nz + d;
                float m2p = -2.0f * proj;
                int o = i * 6 + k;
                tx[o] = fmaf(m2p, nx, px[i]);
                ty[o] = fmaf(m2p, ny, py[i]);
                tz[o] = fmaf(m2p, nz, pz[i]);
            }
            // 3 quaternion conjugations: o = (q * (0,p) * q_conj)[1:]
#pragma unroll
            for (int k = 0; k < 3; ++k) {
                float qw = Q[4 * k + 0], qx = Q[4 * k + 1], qy = Q[4 * k + 2], qz = Q[4 * k + 3];
                float rw = -(qx * px[i] + qy * py[i] + qz * pz[i]);
                float rx = qw * px[i] + qy * pz[i] - qz * py[i];
                float ry = qw * py[i] - qx * pz[i] + qz * px[i];
                float rz = qw * pz[i] + qx * py[i] - qy * px[i];
                int o = i * 6 + 3 + k;
                tx[o] = -rw * qx + rx * qw - ry * qz + rz * qy;
                ty[o] = -rw * qy + rx * qz + ry * qw - rz * qx;
                tz[o] = -rw * qz - rx * qy + ry * qx + rz * qw;
            }
        }

        // 24 independent gathers; compute all addresses first so the compiler
        // can batch-issue the loads.
        int base[24];
#pragma unroll
        for (int o = 0; o < 24; ++o) {
            float f0 = rintf((tx[o] - g0) * s0);  // round-half-to-even == jnp.round
            float f1 = rintf((ty[o] - g1) * s1);
            float f2 = rintf((tz[o] - g2) * s2);
            f0 = fminf(fmaxf(f0, 0.0f), 255.0f);
            f1 = fminf(fmaxf(f1, 0.0f), 255.0f);
            f2 = fminf(fmaxf(f2, 0.0f), 255.0f);
            int i0 = (int)f0, i1 = (int)f1, i2 = (int)f2;
            base[o] = ((i0 * RGRID + i1) * RGRID + i2) * 3;
        }
        float partial[4] = {0.0f, 0.0f, 0.0f, 0.0f};
#pragma unroll
        for (int o = 0; o < 24; ++o) {
            float cx = grid[base[o] + 0];
            float cy = grid[base[o] + 1];
            float cz = grid[base[o] + 2];
            float dx = tx[o] - cx, dy = ty[o] - cy, dz = tz[o] - cz;
            partial[o / 6] += sqrtf(fmaf(dx, dx, fmaf(dy, dy, dz * dz)));
        }
#pragma unroll
        for (int i = 0; i < 4; ++i)
            if (i < npts) lsum += partial[i];
    }

    // wave(64) shuffle reduce -> LDS -> one atomic per block
#pragma unroll
    for (int off = 32; off > 0; off >>= 1)
        lsum += __shfl_down(lsum, off, 64);
    __shared__ float wsum[4];
    int lane = threadIdx.x & 63;
    int wid  = threadIdx.x >> 6;
    if (lane == 0) wsum[wid] = lsum;
    __syncthreads();

    if (threadIdx.x == 0) {
        atomicAdd(acc, wsum[0] + wsum[1] + wsum[2] + wsum[3]);
        __threadfence();
        unsigned prev = atomicAdd((unsigned*)(acc + 1), 1u);
        if (prev == gridDim.x - 1) {
            // Last block: all other blocks' adds are visible (fence + atomic chain).
            float total = atomicAdd(acc, 0.0f);
            float sd = total / (float)N;

            // regularizer: sum((n n^T - I)^2) with UN-normalized plane normals
            float sA = 0.0f;
#pragma unroll
            for (int i = 0; i < 3; ++i)
#pragma unroll
                for (int j = 0; j < 3; ++j) {
                    float a = P[4 * i + 0] * P[4 * j + 0] + P[4 * i + 1] * P[4 * j + 1]
                            + P[4 * i + 2] * P[4 * j + 2] - (i == j ? 1.0f : 0.0f);
                    sA += a * a;
                }
            // sum((v v^T - I)^2) with normalized axis vectors
            float v[3][3];
#pragma unroll
            for (int i = 0; i < 3; ++i) {
                float vx = Q[4 * i + 1], vy = Q[4 * i + 2], vz = Q[4 * i + 3];
                float nrm = sqrtf(vx * vx + vy * vy + vz * vz);
                nrm = fmaxf(nrm, 1e-12f);
                v[i][0] = vx / nrm; v[i][1] = vy / nrm; v[i][2] = vz / nrm;
            }
            float sB = 0.0f;
#pragma unroll
            for (int i = 0; i < 3; ++i)
#pragma unroll
                for (int j = 0; j < 3; ++j) {
                    float b = v[i][0] * v[j][0] + v[i][1] * v[j][1] + v[i][2] * v[j][2]
                            - (i == j ? 1.0f : 0.0f);
                    sB += b * b;
                }

            float r = sA + sB;
            out[0] = sd + 25.0f * r;   // final_loss
            out[1] = sd;               // total_loss_sd
            out[2] = r;                // total_loss_r
        }
    }
}

extern "C" void kernel_launch(void* const* d_in, const int* in_sizes, int n_in,
                              void* d_out, int out_size, void* d_ws, size_t ws_size,
                              hipStream_t stream) {
    const float* planes = (const float*)d_in[0];   // (1,3,4)
    const float* axes   = (const float*)d_in[1];   // (1,3,4)
    const float* pts    = (const float*)d_in[2];   // (N,3)
    const float* grid   = (const float*)d_in[3];   // (256,256,256,3)
    const float* gmin   = (const float*)d_in[4];   // (3,)
    const float* gmax   = (const float*)d_in[5];   // (3,)
    float* out = (float*)d_out;
    float* acc = (float*)d_ws;                     // [0]=sum, [1]=ticket

    int N = in_sizes[2] / 3;

    hipMemsetAsync(acc, 0, 2 * sizeof(float), stream);

    int nthreads = (N + PTS_PER_THREAD - 1) / PTS_PER_THREAD;
    int blocks = (nthreads + 255) / 256;
    hipLaunchKernelGGL(symloss_main, dim3(blocks), dim3(256), 0, stream,
                       planes, axes, pts, grid, gmin, gmax, acc, out, N);
}

// Round 4
// 260.119 us; speedup vs baseline: 1.2699x; 1.1241x over previous
//
#include <hip/hip_runtime.h>
#include <math.h>

// SymmetryLoss: 3 plane reflections + 3 quaternion rotations of 1e6 points,
// nearest-grid-point distance (256^3x3 grid gather), plus tiny 3x3 regularizer.
// Gather-latency bound on random 12B gathers into the 201MB grid (~50-60
// sustained outstanding misses/CU = TCP miss-queue floor; not BW-bound).
// R6: main kernel = exact R0/R2 structure (PTS=4, 24-deep single gather
// batch, no VGPR cap, NO fences/tickets -- R5 isolated the last-block
// __threadfence fold as a +26us regression via per-block L2 writeback).
// Delta vs R0: per-block result SLOTS (plain stores) instead of
// memset+atomicAdd -> the 8B memset dispatch disappears; final kernel
// (256 threads) sums slots. 2 dispatches, 0 fences, 0 atomics.

#define RGRID 256
#define PTS_PER_THREAD 4

__global__ void __launch_bounds__(256)
symloss_main(const float* __restrict__ planes, const float* __restrict__ axes,
             const float* __restrict__ pts, const float* __restrict__ grid,
             const float* __restrict__ gmin, const float* __restrict__ gmax,
             float* __restrict__ slots, int N) {
    // Uniform-address parameter loads -> scalar registers
    float P[12], Q[12];
#pragma unroll
    for (int i = 0; i < 12; ++i) { P[i] = planes[i]; Q[i] = axes[i]; }
    const float g0 = gmin[0], g1 = gmin[1], g2 = gmin[2];
    const float s0 = 255.0f / (gmax[0] - g0);
    const float s1 = 255.0f / (gmax[1] - g1);
    const float s2 = 255.0f / (gmax[2] - g2);

    const int t  = blockIdx.x * blockDim.x + threadIdx.x;
    const int p0 = t * PTS_PER_THREAD;

    float lsum = 0.0f;
    if (p0 < N) {
        float px[4], py[4], pz[4];
        int npts;
        if (p0 + 3 < N) {
            // 4 points = 12 floats = 3 aligned float4 loads
            const float4* pts4 = (const float4*)pts;
            float4 a = pts4[3 * t + 0];
            float4 b = pts4[3 * t + 1];
            float4 c = pts4[3 * t + 2];
            px[0] = a.x; py[0] = a.y; pz[0] = a.z;
            px[1] = a.w; py[1] = b.x; pz[1] = b.y;
            px[2] = b.z; py[2] = b.w; pz[2] = c.x;
            px[3] = c.y; py[3] = c.z; pz[3] = c.w;
            npts = 4;
        } else {
            npts = N - p0;
#pragma unroll
            for (int i = 0; i < 4; ++i) {
                int p = p0 + (i < npts ? i : 0);   // clamp: duplicates are masked below
                px[i] = pts[3 * p + 0];
                py[i] = pts[3 * p + 1];
                pz[i] = pts[3 * p + 2];
            }
        }

        // 24 transformed points
        float tx[24], ty[24], tz[24];
#pragma unroll
        for (int i = 0; i < 4; ++i) {
            // 3 plane reflections: tp = p - 2*(p.n + d)*n
#pragma unroll
            for (int k = 0; k < 3; ++k) {
                float nx = P[4 * k + 0], ny = P[4 * k + 1], nz = P[4 * k + 2], d = P[4 * k + 3];
                float proj = px[i] * nx + py[i] * ny + pz[i] * nz + d;
                float m2p = -2.0f * proj;
                int o = i * 6 + k;
                tx[o] = fmaf(m2p, nx, px[i]);
                ty[o] = fmaf(m2p, ny, py[i]);
                tz[o] = fmaf(m2p, nz, pz[i]);
            }
            // 3 quaternion conjugations: o = (q * (0,p) * q_conj)[1:]
#pragma unroll
            for (int k = 0; k < 3; ++k) {
                float qw = Q[4 * k + 0], qx = Q[4 * k + 1], qy = Q[4 * k + 2], qz = Q[4 * k + 3];
                float rw = -(qx * px[i] + qy * py[i] + qz * pz[i]);
                float rx = qw * px[i] + qy * pz[i] - qz * py[i];
                float ry = qw * py[i] - qx * pz[i] + qz * px[i];
                float rz = qw * pz[i] + qx * py[i] - qy * px[i];
                int o = i * 6 + 3 + k;
                tx[o] = -rw * qx + rx * qw - ry * qz + rz * qy;
                ty[o] = -rw * qy + rx * qz + ry * qw - rz * qx;
                tz[o] = -rw * qz - rx * qy + ry * qx + rz * qw;
            }
        }

        // 24 independent gathers; compute all addresses first so the compiler
        // can batch-issue the loads.
        int base[24];
#pragma unroll
        for (int o = 0; o < 24; ++o) {
            float f0 = rintf((tx[o] - g0) * s0);  // round-half-to-even == jnp.round
            float f1 = rintf((ty[o] - g1) * s1);
            float f2 = rintf((tz[o] - g2) * s2);
            f0 = fminf(fmaxf(f0, 0.0f), 255.0f);
            f1 = fminf(fmaxf(f1, 0.0f), 255.0f);
            f2 = fminf(fmaxf(f2, 0.0f), 255.0f);
            int i0 = (int)f0, i1 = (int)f1, i2 = (int)f2;
            base[o] = ((i0 * RGRID + i1) * RGRID + i2) * 3;
        }
        float partial[4] = {0.0f, 0.0f, 0.0f, 0.0f};
#pragma unroll
        for (int o = 0; o < 24; ++o) {
            float cx = grid[base[o] + 0];
            float cy = grid[base[o] + 1];
            float cz = grid[base[o] + 2];
            float dx = tx[o] - cx, dy = ty[o] - cy, dz = tz[o] - cz;
            partial[o / 6] += sqrtf(fmaf(dx, dx, fmaf(dy, dy, dz * dz)));
        }
#pragma unroll
        for (int i = 0; i < 4; ++i)
            if (i < npts) lsum += partial[i];
    }

    // wave(64) shuffle reduce -> LDS -> one plain store per block (no atomic,
    // no fence; dispatch boundary gives the final kernel coherence)
#pragma unroll
    for (int off = 32; off > 0; off >>= 1)
        lsum += __shfl_down(lsum, off, 64);
    __shared__ float wsum[4];
    int lane = threadIdx.x & 63;
    int wid  = threadIdx.x >> 6;
    if (lane == 0) wsum[wid] = lsum;
    __syncthreads();
    if (threadIdx.x == 0)
        slots[blockIdx.x] = wsum[0] + wsum[1] + wsum[2] + wsum[3];
}

__global__ void __launch_bounds__(256)
symloss_final(const float* __restrict__ planes,
              const float* __restrict__ axes,
              const float* __restrict__ slots, int nblocks,
              float* __restrict__ out, float invN) {
    // Sum per-block partials (every slot [0,nblocks) was written this
    // iteration -- no stale-poison hazard).
    float s = 0.0f;
    for (int i = threadIdx.x; i < nblocks; i += 256)
        s += slots[i];
#pragma unroll
    for (int off = 32; off > 0; off >>= 1)
        s += __shfl_down(s, off, 64);
    __shared__ float wsum[4];
    int lane = threadIdx.x & 63;
    int wid  = threadIdx.x >> 6;
    if (lane == 0) wsum[wid] = s;
    __syncthreads();

    if (threadIdx.x == 0) {
        float sd = (wsum[0] + wsum[1] + wsum[2] + wsum[3]) * invN;

        float n[3][3];
#pragma unroll
        for (int i = 0; i < 3; ++i)
#pragma unroll
            for (int j = 0; j < 3; ++j) n[i][j] = planes[4 * i + j];

        float sA = 0.0f;
#pragma unroll
        for (int i = 0; i < 3; ++i)
#pragma unroll
            for (int j = 0; j < 3; ++j) {
                float a = n[i][0] * n[j][0] + n[i][1] * n[j][1] + n[i][2] * n[j][2]
                          - (i == j ? 1.0f : 0.0f);
                sA += a * a;
            }

        float v[3][3];
#pragma unroll
        for (int i = 0; i < 3; ++i) {
            float vx = axes[4 * i + 1], vy = axes[4 * i + 2], vz = axes[4 * i + 3];
            float nrm = sqrtf(vx * vx + vy * vy + vz * vz);
            nrm = fmaxf(nrm, 1e-12f);
            v[i][0] = vx / nrm; v[i][1] = vy / nrm; v[i][2] = vz / nrm;
        }
        float sB = 0.0f;
#pragma unroll
        for (int i = 0; i < 3; ++i)
#pragma unroll
            for (int j = 0; j < 3; ++j) {
                float b = v[i][0] * v[j][0] + v[i][1] * v[j][1] + v[i][2] * v[j][2]
                          - (i == j ? 1.0f : 0.0f);
                sB += b * b;
            }

        float r = sA + sB;
        out[0] = sd + 25.0f * r;   // final_loss
        out[1] = sd;               // total_loss_sd
        out[2] = r;                // total_loss_r
    }
}

extern "C" void kernel_launch(void* const* d_in, const int* in_sizes, int n_in,
                              void* d_out, int out_size, void* d_ws, size_t ws_size,
                              hipStream_t stream) {
    const float* planes = (const float*)d_in[0];   // (1,3,4)
    const float* axes   = (const float*)d_in[1];   // (1,3,4)
    const float* pts    = (const float*)d_in[2];   // (N,3)
    const float* grid   = (const float*)d_in[3];   // (256,256,256,3)
    const float* gmin   = (const float*)d_in[4];   // (3,)
    const float* gmax   = (const float*)d_in[5];   // (3,)
    float* out   = (float*)d_out;
    float* slots = (float*)d_ws;                   // per-block partials

    int N = in_sizes[2] / 3;

    int nthreads = (N + PTS_PER_THREAD - 1) / PTS_PER_THREAD;
    int blocks = (nthreads + 255) / 256;
    hipLaunchKernelGGL(symloss_main, dim3(blocks), dim3(256), 0, stream,
                       planes, axes, pts, grid, gmin, gmax, slots, N);
    hipLaunchKernelGGL(symloss_final, dim3(1), dim3(256), 0, stream,
                       planes, axes, slots, blocks, out, 1.0f / (float)N);
}